// Round 1
// baseline (102.525 us; speedup 1.0000x reference)
//
#include <hip/hip_runtime.h>
#include <math.h>

// Problem constants
#define B_    4
#define T_    2048
#define D_    512
#define H_    4
#define ROWS_ 8192
#define CHSZ_ 64      // timesteps per chunk (single-wave scan)
#define NCHK_ 32      // chunks per (b,h)

typedef unsigned short ushort_t;
typedef unsigned int   uint_t;
typedef __attribute__((ext_vector_type(8))) __bf16         bfx8;
typedef __attribute__((ext_vector_type(8))) unsigned short u16x8;
typedef __attribute__((ext_vector_type(4))) float          fx4;

__device__ __forceinline__ ushort_t f2bf(float f) {
    union { float f; uint_t u; } v; v.f = f;
    return (ushort_t)((v.u + 0x7FFFu + ((v.u >> 16) & 1u)) >> 16);
}
// RNE via hardware cvt (identical rounding to f2bf, ~1 VALU instead of ~4)
__device__ __forceinline__ ushort_t f2bfc(float f) {
    union { __bf16 h; ushort_t u; } v; v.h = (__bf16)f; return v.u;
}
__device__ __forceinline__ float bf2f(ushort_t u) {
    union { uint_t u; float f; } v; v.u = ((uint_t)u) << 16; return v.f;
}

// ---------------------------------------------------------------------------
// pack_w: weights only (coalesced transpose/convert — R9 lesson). UNCHANGED.
// ---------------------------------------------------------------------------
__global__ __launch_bounds__(256) void pack_w(const float* __restrict__ Wq,
                                              const float* __restrict__ Wk,
                                              const float* __restrict__ Wv,
                                              const float* __restrict__ Wg,
                                              const float* __restrict__ Wo,
                                              ushort_t* __restrict__ WcatT2,
                                              ushort_t* __restrict__ WoT) {
    int idx = blockIdx.x * 256 + threadIdx.x;
    if (idx < 256 * 512) {
        int n = idx >> 9, d = idx & 511;
        int h = n >> 6, r = n & 63, part = r >> 4, j = r & 15;
        int col = h * 16 + j;
        const float* W = (part == 0) ? Wq : (part == 1) ? Wk : (part == 2) ? Wv : Wg;
        WcatT2[idx] = f2bf(W[(size_t)d * 64 + col]);
    } else {
        int r = idx - 256 * 512;          // 0..32767 = n*64 + k
        int n = r >> 6, k = r & 63;
        WoT[r] = f2bf(Wo[(size_t)k * 512 + n]);
    }
}

// ---------------------------------------------------------------------------
// gemm_scanA V2: same math, restructured K-loop pipeline.
//   - double-buffered LDS (As[2]/Bs[2]), ONE raw s_barrier per K-step
//     (was 2 __syncthreads, each with an implicit s_waitcnt vmcnt(0) drain)
//   - explicit `s_waitcnt lgkmcnt(0)` + sched_barrier(0) fences instead of the
//     compiler's full vmcnt drain -> prefetch loads stay in flight across
//     barriers (counted-vmcnt, T4)
//   - depth-2 register prefetch: tiles it+1 and it+2 outstanding -> ~2
//     iterations (~600+ cyc) of latency window, covers L3/HBM latency
//   - f2bfc (hw RNE cvt) in the hot commit + epilogue paths
// ---------------------------------------------------------------------------
__global__ __launch_bounds__(256) void gemm_scanA(const float* __restrict__ x,
                                                  const float* __restrict__ Wa,
                                                  const float* __restrict__ ba,
                                                  const ushort_t* __restrict__ WcatT2,
                                                  float* __restrict__ stateWS,
                                                  float* __restrict__ chunkSum,
                                                  ushort_t* __restrict__ gBuf) {
    __shared__ ushort_t As[2][64 * 72];   // As[0] reused as Ct after K-loop
    __shared__ ushort_t Bs[2][64 * 72];
    __shared__ float s_wa[512];
    __shared__ float s_a[64];

    const int rc = blockIdx.x & 127;    // row chunk (b*32 + chunk)
    const int h  = blockIdx.x >> 7;
    const int m0 = rc * 64;
    const int n0 = h * 64;
    const int b  = rc >> 5, chunk = rc & 31;
    const int bh = b * 4 + h;

    const int tid = threadIdx.x;
    const int wave = tid >> 6, lane = tid & 63;
    const int fr = lane & 15, quad = lane >> 4;
    const int sr = tid >> 3, sc = (tid & 7) * 8;   // sr 0..31

    fx4 acc[4];
    #pragma unroll
    for (int j = 0; j < 4; j++) acc[j] = (fx4)0.f;

    float pa[2] = {0.f, 0.f};   // partial x·Wa[:,h] per staged row

    // depth-2 prefetch register banks
    float4 raF[2][2][2];   // [bank][s][half]
    u16x8  rb[2][2];       // [bank][s]

    // issue tiles 0 and 1 (stay in flight across the raw barrier below)
    #pragma unroll
    for (int p = 0; p < 2; p++) {
        const int k0 = p * 64;
        #pragma unroll
        for (int s = 0; s < 2; s++) {
            const float* xp = x + (size_t)(m0 + s * 32 + sr) * D_ + k0 + sc;
            raF[p][s][0] = *(const float4*)xp;
            raF[p][s][1] = *(const float4*)(xp + 4);
            rb[p][s] = *(const u16x8*)(WcatT2 + (size_t)(n0 + s * 32 + sr) * D_ + k0 + sc);
        }
    }

    // cache Wa[:,h] in LDS (512 floats, once)
    s_wa[tid * 2]     = Wa[(size_t)(tid * 2) * 4 + h];
    s_wa[tid * 2 + 1] = Wa[(size_t)(tid * 2 + 1) * 4 + h];

    // raw barrier: drain LDS writes only; global prefetch stays outstanding
    asm volatile("s_waitcnt lgkmcnt(0)" ::: "memory");
    __builtin_amdgcn_sched_barrier(0);
    __builtin_amdgcn_s_barrier();
    __builtin_amdgcn_sched_barrier(0);

    #pragma unroll
    for (int it = 0; it < 8; it++) {
        const int cur = it & 1;
        const int kb = it * 64 + sc;
        // commit bank[cur] -> LDS buf[cur] (fp32 -> bf16) + a-decay partials.
        // Compiler emits a COUNTED vmcnt wait here (only this tile's loads;
        // the next tile's loads remain in flight).
        float4 wa0 = *(const float4*)&s_wa[kb];
        float4 wa1 = *(const float4*)&s_wa[kb + 4];
        float wav[8] = {wa0.x, wa0.y, wa0.z, wa0.w, wa1.x, wa1.y, wa1.z, wa1.w};
        #pragma unroll
        for (int s = 0; s < 2; s++) {
            float xv[8] = {raF[cur][s][0].x, raF[cur][s][0].y, raF[cur][s][0].z, raF[cur][s][0].w,
                           raF[cur][s][1].x, raF[cur][s][1].y, raF[cur][s][1].z, raF[cur][s][1].w};
            u16x8 u;
            #pragma unroll
            for (int j = 0; j < 8; j++) {
                u[j] = f2bfc(xv[j]);
                pa[s] = fmaf(xv[j], wav[j], pa[s]);
            }
            *(u16x8*)&As[cur][(s * 32 + sr) * 72 + sc] = u;
            *(u16x8*)&Bs[cur][(s * 32 + sr) * 72 + sc] = rb[cur][s];
        }
        // ONE barrier per K-step; no vmcnt drain (tile it+1 loads in flight)
        asm volatile("s_waitcnt lgkmcnt(0)" ::: "memory");
        __builtin_amdgcn_sched_barrier(0);
        __builtin_amdgcn_s_barrier();
        __builtin_amdgcn_sched_barrier(0);
        // reissue bank[cur] for tile it+2 (window: ~2 full iterations)
        if (it < 6) {
            const int k0 = (it + 2) * 64;
            #pragma unroll
            for (int s = 0; s < 2; s++) {
                const float* xp = x + (size_t)(m0 + s * 32 + sr) * D_ + k0 + sc;
                raF[cur][s][0] = *(const float4*)xp;
                raF[cur][s][1] = *(const float4*)(xp + 4);
                rb[cur][s] = *(const u16x8*)(WcatT2 + (size_t)(n0 + s * 32 + sr) * D_ + k0 + sc);
            }
        }
        // compute on buf[cur]: wave w covers rows w*16..w*16+15
        #pragma unroll
        for (int ks = 0; ks < 64; ks += 32) {
            bfx8 af = *(const bfx8*)&As[cur][(wave * 16 + fr) * 72 + ks + quad * 8];
            #pragma unroll
            for (int ni = 0; ni < 4; ni++) {
                bfx8 bfr = *(const bfx8*)&Bs[cur][(ni * 16 + fr) * 72 + ks + quad * 8];
                acc[ni] = __builtin_amdgcn_mfma_f32_16x16x32_bf16(af, bfr, acc[ni], 0, 0, 0);
            }
        }
        // no trailing barrier: buf[cur] is next written at commit(it+2),
        // which is ordered after barrier(it+1) -> all reads of buf[cur] done.
    }

    // C-tile (bf16) into As[0]-as-Ct: row_local x 72 stride, cols 0..63.
    // Safe: last reader of As[0] was MFMA(it=6), ordered before barrier(7).
    #pragma unroll
    for (int ni = 0; ni < 4; ni++)
        #pragma unroll
        for (int r = 0; r < 4; r++) {
            int rl = wave * 16 + quad * 4 + r;
            int cl = ni * 16 + fr;
            As[0][rl * 72 + cl] = f2bfc(acc[ni][r]);
        }

    // finish the a-dots: butterfly over the 8 sc-threads of each row
    #pragma unroll
    for (int s = 0; s < 2; s++) {
        #pragma unroll
        for (int m = 1; m < 8; m <<= 1) pa[s] += __shfl_xor(pa[s], m, 8);
    }
    if ((tid & 7) == 0) {
        const float bah = ba[h];
        #pragma unroll
        for (int s = 0; s < 2; s++) {
            float z = pa[s] + bah;
            s_a[s * 32 + sr] = -(fmaxf(z, 0.f) + log1pf(expf(-fabsf(z))));
        }
    }
    __syncthreads();

    // ---- chunk scan: wave 0 only (64 rows, single wave, one frame Mc) ----
    if (wave == 0) {
        const ushort_t* ct = &As[0][lane * 72];
        u16x8 q0 = *(const u16x8*)(ct +  0), q1 = *(const u16x8*)(ct +  8);
        u16x8 k0 = *(const u16x8*)(ct + 16), k1 = *(const u16x8*)(ct + 24);
        u16x8 v0 = *(const u16x8*)(ct + 32), v1 = *(const u16x8*)(ct + 40);
        float bid = 0.f;
        float v[16];
        #pragma unroll
        for (int j = 0; j < 8; j++) {
            bid = fmaf(bf2f(q0[j]), bf2f(k0[j]), bid);
            bid = fmaf(bf2f(q1[j]), bf2f(k1[j]), bid);
            v[j]     = bf2f(v0[j]);
            v[8 + j] = bf2f(v1[j]);
        }
        bid *= 0.25f;
        float a = s_a[lane];

        // cumA inclusive scan (64 lanes)
        float ca = a;
        #pragma unroll
        for (int off = 1; off < 64; off <<= 1) {
            float up = __shfl_up(ca, off);
            if (lane >= off) ca += up;
        }

        float lg = bid - ca;      // chunk-local log-weight

        // chunk max Mc (frame; spread over 64 rows ~45 << 87)
        float Mc = lg;
        #pragma unroll
        for (int off = 32; off; off >>= 1) Mc = fmaxf(Mc, __shfl_xor(Mc, off));

        // plain prefix sums of (d, n[16]) = e^{lg-Mc} * (1, v)
        float d = __expf(lg - Mc);
        float n[16];
        #pragma unroll
        for (int j = 0; j < 16; j++) n[j] = d * v[j];
        #pragma unroll
        for (int off = 1; off < 64; off <<= 1) {
            float ud = __shfl_up(d, off);
            float un[16];
            #pragma unroll
            for (int j = 0; j < 16; j++) un[j] = __shfl_up(n[j], off);
            if (lane >= off) {
                d += ud;
                #pragma unroll
                for (int j = 0; j < 16; j++) n[j] += un[j];
            }
        }

        // write per-row state (frame Mc), g-tile, chunk summary
        const int t = chunk * CHSZ_ + lane;
        const size_t eidx = (size_t)bh * T_ + t;
        stateWS[eidx] = Mc;
        stateWS[32768 + eidx] = d;
        #pragma unroll
        for (int j = 0; j < 16; j++) stateWS[(size_t)(2 + j) * 32768 + eidx] = n[j];

        u16x8 g0 = *(const u16x8*)(ct + 48), g1 = *(const u16x8*)(ct + 56);
        *(u16x8*)(gBuf + eidx * 16)     = g0;
        *(u16x8*)(gBuf + eidx * 16 + 8) = g1;

        if (lane == 63) {
            float* cs = chunkSum + (size_t)(bh * NCHK_ + chunk) * 20;
            cs[0] = Mc; cs[1] = d;
            #pragma unroll
            for (int j = 0; j < 16; j++) cs[2 + j] = n[j];
            cs[18] = ca;   // chunk total of a
        }
    }
}

// ---------------------------------------------------------------------------
// scan_gemm: fused look-back + combine + gate + output GEMM. UNCHANGED.
// ---------------------------------------------------------------------------
__global__ __launch_bounds__(256) void scan_gemm(const float* __restrict__ stateWS,
                                                 const float* __restrict__ chunkSum,
                                                 const ushort_t* __restrict__ gBuf,
                                                 const float* __restrict__ bg,
                                                 const ushort_t* __restrict__ WoT,
                                                 float* __restrict__ C) {
    __shared__ ushort_t Ys[64 * 72];
    __shared__ ushort_t Bs[128 * 72];
    __shared__ float s_pref[4][18];

    const int m0 = blockIdx.y * 64;     // global row base
    const int n0 = blockIdx.x * 128;    // output column base
    const int b  = m0 >> 11;            // batch
    const int tt = m0 & 2047;           // batch-local t of tile row 0
    const int chunk = tt >> 6;          // containing chunk (0..31)

    const int tid = threadIdx.x;
    const int wave = tid >> 6, lane = tid & 63;

    // stage WoT rows n0..n0+127 (cols of Wo), K=64 — vector loads
    const int sr = tid >> 3, sc = (tid & 7) * 8;
    #pragma unroll
    for (int s = 0; s < 4; s++) {
        int rr = s * 32 + sr;
        *(u16x8*)&Bs[rr * 72 + sc] = *(const u16x8*)(WoT + (size_t)(n0 + rr) * 64 + sc);
    }

    // per-(head,row) state loads: head = wave, row = lane (coalesced per plane)
    const int h = wave, r = lane;
    const int bh = b * 4 + h;
    const size_t eidx = (size_t)bh * T_ + tt + r;
    float m_row = stateWS[eidx];
    float d_row = stateWS[32768 + eidx];
    float n_row[16];
    #pragma unroll
    for (int j = 0; j < 16; j++) n_row[j] = stateWS[(size_t)(2 + j) * 32768 + eidx];
    u16x8 g0 = *(const u16x8*)(gBuf + eidx * 16);
    u16x8 g1 = *(const u16x8*)(gBuf + eidx * 16 + 8);

    // waves 0,1: parallel look-back, 32-lane group per head
    if (wave < 2) {
        const int hh = wave * 2 + (lane >> 5), p = lane & 31;
        const int bhh = b * 4 + hh;
        float mf = -1e30f, dd = 0.f, aT = 0.f;
        float nn[16];
        #pragma unroll
        for (int j = 0; j < 16; j++) nn[j] = 0.f;
        if (p < chunk) {
            const float* cs = chunkSum + (size_t)(bhh * NCHK_ + p) * 20;
            mf = cs[0]; dd = cs[1];
            #pragma unroll
            for (int j = 0; j < 16; j++) nn[j] = cs[2 + j];
            aT = cs[18];
        }
        // suffix sums of aTot within the 32-lane head group
        float off = aT;
        #pragma unroll
        for (int s = 1; s < 32; s <<= 1) {
            float t2 = __shfl_down(off, s, 32);
            if (p + s < chunk) off += t2;
        }
        if (p < chunk) mf += off;   // shift into this chunk's local frame
        // tree-combine the 32 lanes of each head group
        #pragma unroll
        for (int s = 1; s < 32; s <<= 1) {
            float m2 = __shfl_xor(mf, s, 32);
            float d2 = __shfl_xor(dd, s, 32);
            float mx = fmaxf(mf, m2);
            float al = __expf(mf - mx), be = __expf(m2 - mx);
            #pragma unroll
            for (int j = 0; j < 16; j++) {
                float n2 = __shfl_xor(nn[j], s, 32);
                nn[j] = nn[j] * al + n2 * be;
            }
            dd = dd * al + d2 * be;
            mf = mx;
        }
        if (p == 0) {
            s_pref[hh][0] = mf; s_pref[hh][1] = dd;
            #pragma unroll
            for (int j = 0; j < 16; j++) s_pref[hh][2 + j] = nn[j];
        }
    }
    __syncthreads();

    // combine prefix with row state, gate, write Y-tile to LDS
    {
        const float M = s_pref[h][0], D = s_pref[h][1];
        const float mx = fmaxf(M, m_row);
        const float al = __expf(M - mx), be = __expf(m_row - mx);
        const float invd = 1.f / (D * al + d_row * be);
        u16x8 o0, o1;
        #pragma unroll
        for (int j = 0; j < 16; j++) {
            float Nj = s_pref[h][2 + j] * al + n_row[j] * be;
            float gpre = ((j < 8) ? bf2f(g0[j]) : bf2f(g1[j - 8])) + bg[h * 16 + j];
            float gate = 1.f / (1.f + __expf(-gpre));
            ushort_t yb = f2bf(Nj * invd * gate);
            if (j < 8) o0[j] = yb; else o1[j - 8] = yb;
        }
        *(u16x8*)&Ys[r * 72 + h * 16]     = o0;
        *(u16x8*)&Ys[r * 72 + h * 16 + 8] = o1;
    }
    __syncthreads();

    // GEMM: out-tile (64 x 128) = Ys (64 x 64) @ Bs(128 x 64)^T
    const int wr = wave >> 1, wc = wave & 1;
    const int fr = lane & 15, quad = lane >> 4;
    fx4 acc[2][4];
    #pragma unroll
    for (int i = 0; i < 2; i++)
        #pragma unroll
        for (int j = 0; j < 4; j++) acc[i][j] = (fx4)0.f;

    #pragma unroll
    for (int ks = 0; ks < 64; ks += 32) {
        bfx8 af[2], bfr[4];
        #pragma unroll
        for (int mi = 0; mi < 2; mi++)
            af[mi] = *(const bfx8*)&Ys[(wr * 32 + mi * 16 + fr) * 72 + ks + quad * 8];
        #pragma unroll
        for (int ni = 0; ni < 4; ni++)
            bfr[ni] = *(const bfx8*)&Bs[(wc * 64 + ni * 16 + fr) * 72 + ks + quad * 8];
        #pragma unroll
        for (int mi = 0; mi < 2; mi++)
            #pragma unroll
            for (int ni = 0; ni < 4; ni++)
                acc[mi][ni] = __builtin_amdgcn_mfma_f32_16x16x32_bf16(af[mi], bfr[ni], acc[mi][ni], 0, 0, 0);
    }

    #pragma unroll
    for (int mi = 0; mi < 2; mi++)
        #pragma unroll
        for (int ni = 0; ni < 4; ni++)
            #pragma unroll
            for (int rr = 0; rr < 4; rr++) {
                int orow = m0 + wr * 32 + mi * 16 + quad * 4 + rr;
                int ocol = n0 + wc * 64 + ni * 16 + fr;
                C[(size_t)orow * D_ + ocol] = acc[mi][ni][rr];
            }
}

// ---------------------------------------------------------------------------
extern "C" void kernel_launch(void* const* d_in, const int* in_sizes, int n_in,
                              void* d_out, int out_size, void* d_ws, size_t ws_size,
                              hipStream_t stream) {
    const float* x  = (const float*)d_in[0];
    const float* Wq = (const float*)d_in[1];
    const float* Wk = (const float*)d_in[2];
    const float* Wv = (const float*)d_in[3];
    const float* Wa = (const float*)d_in[4];
    const float* ba = (const float*)d_in[5];
    const float* Wg = (const float*)d_in[6];
    const float* bg = (const float*)d_in[7];
    const float* Wo = (const float*)d_in[8];
    float* out = (float*)d_out;

    char* w = (char*)d_ws;
    ushort_t* WcatT2   = (ushort_t*)w;  w += 256 * 512 * 2;             // 256 KiB
    ushort_t* WoT      = (ushort_t*)w;  w += 512 * 64 * 2;              // 64 KiB
    float*    stateWS  = (float*)w;     w += (size_t)18 * 32768 * 4;    // 2.25 MiB
    float*    chunkSum = (float*)w;     w += 512 * 20 * 4;              // 40 KiB
    ushort_t* gBuf     = (ushort_t*)w;  w += (size_t)32768 * 16 * 2;    // 1 MiB

    pack_w<<<640, 256, 0, stream>>>(Wq, Wk, Wv, Wg, Wo, WcatT2, WoT);
    gemm_scanA<<<512, 256, 0, stream>>>(x, Wa, ba, WcatT2,
                                        stateWS, chunkSum, gBuf);
    scan_gemm<<<dim3(4, 128), 256, 0, stream>>>(stateWS, chunkSum, gBuf, bg, WoT, out);
}